// Round 1
// baseline (1370.663 us; speedup 1.0000x reference)
//
#include <hip/hip_runtime.h>
#include <stdint.h>

#define TOKENS 8192
#define IN_F   4096
#define OUT_F  11008
#define PACKED (OUT_F / 2)

typedef __bf16   bf16x8 __attribute__((ext_vector_type(8)));
typedef float    f32x4  __attribute__((ext_vector_type(4)));
typedef uint16_t u16x8  __attribute__((ext_vector_type(8)));

__device__ __forceinline__ uint16_t f32_to_bf16(float f) {
    union { float f; uint32_t u; } c; c.f = f;
    uint32_t r = c.u + 0x7FFFu + ((c.u >> 16) & 1u);
    return (uint16_t)(r >> 16);
}

// ---------------- kernel 1: x fp32 -> bf16 ----------------
__global__ __launch_bounds__(256) void xcvt_kernel(const float* __restrict__ x,
                                                   uint16_t* __restrict__ xb) {
    size_t base = ((size_t)blockIdx.x * 256 + threadIdx.x) * 8;
    float4 v0 = *(const float4*)(x + base);
    float4 v1 = *(const float4*)(x + base + 4);
    u16x8 o;
    o[0] = f32_to_bf16(v0.x); o[1] = f32_to_bf16(v0.y);
    o[2] = f32_to_bf16(v0.z); o[3] = f32_to_bf16(v0.w);
    o[4] = f32_to_bf16(v1.x); o[5] = f32_to_bf16(v1.y);
    o[6] = f32_to_bf16(v1.z); o[7] = f32_to_bf16(v1.w);
    *(u16x8*)(xb + base) = o;
}

// ------- kernel 2: unpack int4, add offset -> bf16 W^T [OUT_F][IN_F] -------
// scale is NOT applied here (applied exactly in fp32 in the GEMM epilogue).
__global__ __launch_bounds__(256) void wdeq_kernel(const int* __restrict__ wp,
                                                   const float* __restrict__ woff,
                                                   uint16_t* __restrict__ wt) {
    int t  = threadIdx.x;
    int pl = t & 31;   // packed-column within 32-wide tile
    int kc = t >> 5;   // k-chunk of 8 within 64-tall tile
    int p  = blockIdx.y * 32 + pl;
    int k0 = blockIdx.x * 64 + kc * 8;
    float off_e = woff[2 * p];
    float off_o = woff[2 * p + 1];
    u16x8 we, wo;
    #pragma unroll
    for (int i = 0; i < 8; ++i) {
        int v  = wp[(size_t)(k0 + i) * PACKED + p];
        int lo = ((v & 15) ^ 8) - 8;
        int hi = (((v >> 4) & 15) ^ 8) - 8;
        we[i] = f32_to_bf16((float)lo + off_e);
        wo[i] = f32_to_bf16((float)hi + off_o);
    }
    *(u16x8*)(wt + (size_t)(2 * p)     * IN_F + k0) = we;
    *(u16x8*)(wt + (size_t)(2 * p + 1) * IN_F + k0) = wo;
}

// async 16B/lane global -> LDS (lds ptr must be wave-uniform; HW places at base + lane*16)
#define CP16(ldsp, gp)                                                                        \
    __builtin_amdgcn_global_load_lds((const __attribute__((address_space(1))) void*)(gp),     \
                                     (__attribute__((address_space(3))) void*)(ldsp), 16, 0, 0)

// ---------------- kernel 3: bf16 GEMM, m97 structure ----------------
// A = xb [M,K] row-major, B^T = wt [N,K] row-major, out [M,N] fp32.
// 128x128 block tile, BK=32, 4 waves each doing 64x64 via 4x4 of 16x16x32 MFMA.
__global__ __launch_bounds__(256) void gemm_kernel(const uint16_t* __restrict__ xb,
                                                   const uint16_t* __restrict__ wt,
                                                   const float* __restrict__ scale,
                                                   const float* __restrict__ bias,
                                                   float* __restrict__ out) {
    __shared__ uint16_t smem[8192];  // 16 KiB: A tile [128][32] @0, B tile [128][32] @4096 elems

    const int tid  = threadIdx.x;
    const int wid  = tid >> 6;
    const int lane = tid & 63;
    const int quad = lane >> 4;
    const int l15  = lane & 15;

    const int bm = blockIdx.x & 63;   // TOKENS/128 = 64 (m-fastest for B-panel L2 reuse)
    const int bn = blockIdx.x >> 6;   // 0..85
    const int m0 = bm << 7;
    const int n0 = bn << 7;
    const int wm = (wid >> 1) << 6;   // wave m-offset within block (0/64)
    const int wn = (wid & 1) << 6;    // wave n-offset within block (0/64)

    // staging: thread t covers 16 bytes at flat tile offset t*16 (+4096*round)
    const int rowi = tid >> 2;          // tile row 0..63 (round adds 64)
    const int kbyt = (tid & 3) << 4;    // 0..48 bytes within 64B row

    const char* ga0 = (const char*)(xb + (size_t)(m0 + rowi)      * IN_F) + kbyt;
    const char* ga1 = (const char*)(xb + (size_t)(m0 + rowi + 64) * IN_F) + kbyt;
    const char* gb0 = (const char*)(wt + (size_t)(n0 + rowi)      * IN_F) + kbyt;
    const char* gb1 = (const char*)(wt + (size_t)(n0 + rowi + 64) * IN_F) + kbyt;

    char* lds = (char*)smem;
    char* la0 = lds + wid * 1024;           // wave-uniform bases
    char* la1 = lds + 4096  + wid * 1024;
    char* lb0 = lds + 8192  + wid * 1024;
    char* lb1 = lds + 12288 + wid * 1024;

    // fragment read bases (elements): row-major [row][32], 8 contiguous bf16 per lane
    const uint16_t* afrag = smem +        (wm + l15) * 32 + quad * 8;
    const uint16_t* bfrag = smem + 4096 + (wn + l15) * 32 + quad * 8;

    f32x4 acc[4][4] = {};

    for (int k0 = 0; k0 < IN_F; k0 += 32) {
        __syncthreads();                       // previous tile fully consumed
        CP16(la0, ga0); CP16(la1, ga1);
        CP16(lb0, gb0); CP16(lb1, gb1);
        ga0 += 64; ga1 += 64; gb0 += 64; gb1 += 64;   // advance 32 bf16 in k
        __syncthreads();                       // staged data visible (drains vmcnt)

        bf16x8 a[4], b[4];
        #pragma unroll
        for (int i = 0; i < 4; ++i) a[i] = *(const bf16x8*)(afrag + i * 512);  // +16 rows
        #pragma unroll
        for (int i = 0; i < 4; ++i) b[i] = *(const bf16x8*)(bfrag + i * 512);
        #pragma unroll
        for (int mt = 0; mt < 4; ++mt)
            #pragma unroll
            for (int nt = 0; nt < 4; ++nt)
                acc[mt][nt] = __builtin_amdgcn_mfma_f32_16x16x32_bf16(a[mt], b[nt],
                                                                      acc[mt][nt], 0, 0, 0);
    }

    // epilogue: out = acc * scale[n] + bias[n]
    // C/D layout (verified m89/m91): col = lane&15, row = quad*4 + reg
    #pragma unroll
    for (int nt = 0; nt < 4; ++nt) {
        int n    = n0 + wn + nt * 16 + l15;
        float s  = scale[n];
        float bb = bias[n];
        #pragma unroll
        for (int mt = 0; mt < 4; ++mt) {
            int m = m0 + wm + mt * 16 + quad * 4;
            float* o = out + (size_t)m * OUT_F + n;
            #pragma unroll
            for (int r = 0; r < 4; ++r)
                o[(size_t)r * OUT_F] = acc[mt][nt][r] * s + bb;
        }
    }
}

extern "C" void kernel_launch(void* const* d_in, const int* in_sizes, int n_in,
                              void* d_out, int out_size, void* d_ws, size_t ws_size,
                              hipStream_t stream) {
    const float* x     = (const float*)d_in[0];
    const int*   wp    = (const int*)d_in[1];
    const float* scale = (const float*)d_in[2];
    const float* woff  = (const float*)d_in[3];
    const float* bias  = (const float*)d_in[4];
    float* out = (float*)d_out;

    // workspace: xb (64 MiB) then wt (86 MiB); needs ~150 MiB total
    uint16_t* xb = (uint16_t*)d_ws;
    uint16_t* wt = xb + (size_t)TOKENS * IN_F;

    xcvt_kernel<<<(TOKENS * (size_t)IN_F) / (256 * 8), 256, 0, stream>>>(x, xb);
    wdeq_kernel<<<dim3(IN_F / 64, PACKED / 32), 256, 0, stream>>>(wp, woff, wt);
    gemm_kernel<<<(TOKENS / 128) * (OUT_F / 128), 256, 0, stream>>>(xb, wt, scale, bias, out);
}

// Round 2
// 1363.076 us; speedup vs baseline: 1.0056x; 1.0056x over previous
//
#include <hip/hip_runtime.h>
#include <stdint.h>

#define TOKENS 8192
#define IN_F   4096
#define OUT_F  11008
#define PACKED (OUT_F / 2)

typedef __bf16   bf16x8 __attribute__((ext_vector_type(8)));
typedef float    f32x4  __attribute__((ext_vector_type(4)));
typedef uint16_t u16x8  __attribute__((ext_vector_type(8)));

__device__ __forceinline__ uint16_t f32_to_bf16(float f) {
    union { float f; uint32_t u; } c; c.f = f;
    uint32_t r = c.u + 0x7FFFu + ((c.u >> 16) & 1u);
    return (uint16_t)(r >> 16);
}

// ---------------- kernel 1: x fp32 -> bf16 ----------------
__global__ __launch_bounds__(256) void xcvt_kernel(const float* __restrict__ x,
                                                   uint16_t* __restrict__ xb) {
    size_t base = ((size_t)blockIdx.x * 256 + threadIdx.x) * 8;
    float4 v0 = *(const float4*)(x + base);
    float4 v1 = *(const float4*)(x + base + 4);
    u16x8 o;
    o[0] = f32_to_bf16(v0.x); o[1] = f32_to_bf16(v0.y);
    o[2] = f32_to_bf16(v0.z); o[3] = f32_to_bf16(v0.w);
    o[4] = f32_to_bf16(v1.x); o[5] = f32_to_bf16(v1.y);
    o[6] = f32_to_bf16(v1.z); o[7] = f32_to_bf16(v1.w);
    *(u16x8*)(xb + base) = o;
}

// ------- kernel 2: unpack int4, add offset -> bf16 W^T [OUT_F][IN_F] -------
// v2: LDS-transposed so global writes are coalesced (R1: 16 KB-stride scatter
// cost ~350 us). Read coalesced over packed-cols, transpose in LDS, write
// rows k-contiguous (4 lanes = 128 B contiguous).
#define WDQ_STRIDE 72   // bf16 elems per n-row: 64 + 8 pad; 144 B keeps 16 B alignment
__global__ __launch_bounds__(256) void wdeq_kernel(const int* __restrict__ wp,
                                                   const float* __restrict__ woff,
                                                   uint16_t* __restrict__ wt) {
    __shared__ uint16_t tile[64 * WDQ_STRIDE];
    const int t  = threadIdx.x;
    const int p0 = blockIdx.y * 32;           // 32 packed cols = 64 n cols
    const int k0 = blockIdx.x * 64;           // 64 k rows
    const int pl = t & 31;
    const int kb = t >> 5;                    // 0..7
    const int p  = p0 + pl;
    const float off_e = woff[2 * p];
    const float off_o = woff[2 * p + 1];
    #pragma unroll
    for (int j = 0; j < 8; ++j) {
        int kl = j * 8 + kb;
        int v  = wp[(size_t)(k0 + kl) * PACKED + p];
        int lo = ((v & 15) ^ 8) - 8;
        int hi = (((v >> 4) & 15) ^ 8) - 8;
        tile[(2 * pl)     * WDQ_STRIDE + kl] = f32_to_bf16((float)lo + off_e);
        tile[(2 * pl + 1) * WDQ_STRIDE + kl] = f32_to_bf16((float)hi + off_o);
    }
    __syncthreads();
    const int nl = t >> 2;                    // 0..63
    const int kc = (t & 3) * 16;              // 0/16/32/48
    u16x8 w0 = *(const u16x8*)&tile[nl * WDQ_STRIDE + kc];
    u16x8 w1 = *(const u16x8*)&tile[nl * WDQ_STRIDE + kc + 8];
    uint16_t* dst = wt + (size_t)(2 * p0 + nl) * IN_F + k0 + kc;
    *(u16x8*)dst       = w0;
    *(u16x8*)(dst + 8) = w1;
}

// async 16B/lane global -> LDS (lds ptr must be wave-uniform; HW places at base + lane*16)
#define CP16(ldsp, gp)                                                                        \
    __builtin_amdgcn_global_load_lds((const __attribute__((address_space(1))) void*)(gp),     \
                                     (__attribute__((address_space(3))) void*)(ldsp), 16, 0, 0)

// ---------------- kernel 3: bf16 GEMM, m97 structure + XOR bank swizzle ----------------
// A = xb [M,K] row-major, B^T = wt [N,K] row-major, out [M,N] fp32.
// 128x128 block tile, BK=32, 4 waves each doing 64x64 via 4x4 of 16x16x32 MFMA.
// Swizzle: thread t fetches kchunk = (t&3) ^ (row&3), so LDS slot (row, c) holds
// kchunk c^(row&3); fragment reads use quad ^ (row&3). Breaks the 2-bank aliasing
// (R1: 9.0e7 conflict cycles = +4 cyc per ds_read_b128).
__global__ __launch_bounds__(256) void gemm_kernel(const uint16_t* __restrict__ xb,
                                                   const uint16_t* __restrict__ wt,
                                                   const float* __restrict__ scale,
                                                   const float* __restrict__ bias,
                                                   float* __restrict__ out) {
    __shared__ uint16_t smem[8192];  // 16 KiB: A [128][32] @0, B [128][32] @4096 elems

    const int tid  = threadIdx.x;
    const int wid  = tid >> 6;
    const int lane = tid & 63;
    const int quad = lane >> 4;
    const int l15  = lane & 15;

    const int bm = blockIdx.x & 63;   // TOKENS/128 = 64 (m-fastest for B-panel L2 reuse)
    const int bn = blockIdx.x >> 6;   // 0..85
    const int m0 = bm << 7;
    const int n0 = bn << 7;
    const int wm = (wid >> 1) << 6;
    const int wn = (wid & 1) << 6;

    // staging: thread t covers global (row = t>>2, kchunk = (t&3)^(row&3)); LDS slot t*16
    const int rowi = tid >> 2;
    const int kbyt = ((tid & 3) ^ (rowi & 3)) << 4;

    const char* ga0 = (const char*)(xb + (size_t)(m0 + rowi)      * IN_F) + kbyt;
    const char* ga1 = (const char*)(xb + (size_t)(m0 + rowi + 64) * IN_F) + kbyt;
    const char* gb0 = (const char*)(wt + (size_t)(n0 + rowi)      * IN_F) + kbyt;
    const char* gb1 = (const char*)(wt + (size_t)(n0 + rowi + 64) * IN_F) + kbyt;

    char* lds = (char*)smem;
    char* la0 = lds + wid * 1024;
    char* la1 = lds + 4096  + wid * 1024;
    char* lb0 = lds + 8192  + wid * 1024;
    char* lb1 = lds + 12288 + wid * 1024;

    // fragment bases with matching swizzle; (row&3) invariant under +16i and +64
    const int arow = wm + l15;
    const int brow = wn + l15;
    const uint16_t* afrag = smem +        arow * 32 + ((quad ^ (arow & 3)) << 3);
    const uint16_t* bfrag = smem + 4096 + brow * 32 + ((quad ^ (brow & 3)) << 3);

    f32x4 acc[4][4] = {};

    for (int k0 = 0; k0 < IN_F; k0 += 32) {
        __syncthreads();                       // previous tile fully consumed
        CP16(la0, ga0); CP16(la1, ga1);
        CP16(lb0, gb0); CP16(lb1, gb1);
        ga0 += 64; ga1 += 64; gb0 += 64; gb1 += 64;   // advance 32 bf16 in k
        __syncthreads();                       // staged data visible (drains vmcnt)

        bf16x8 a[4], b[4];
        #pragma unroll
        for (int i = 0; i < 4; ++i) a[i] = *(const bf16x8*)(afrag + i * 512);  // +16 rows
        #pragma unroll
        for (int i = 0; i < 4; ++i) b[i] = *(const bf16x8*)(bfrag + i * 512);
        #pragma unroll
        for (int mt = 0; mt < 4; ++mt)
            #pragma unroll
            for (int nt = 0; nt < 4; ++nt)
                acc[mt][nt] = __builtin_amdgcn_mfma_f32_16x16x32_bf16(a[mt], b[nt],
                                                                      acc[mt][nt], 0, 0, 0);
    }

    // epilogue: out = acc * scale[n] + bias[n]
    // C/D layout (verified m89/m91): col = lane&15, row = quad*4 + reg
    #pragma unroll
    for (int nt = 0; nt < 4; ++nt) {
        int n    = n0 + wn + nt * 16 + l15;
        float s  = scale[n];
        float bb = bias[n];
        #pragma unroll
        for (int mt = 0; mt < 4; ++mt) {
            int m = m0 + wm + mt * 16 + quad * 4;
            float* o = out + (size_t)m * OUT_F + n;
            #pragma unroll
            for (int r = 0; r < 4; ++r)
                o[(size_t)r * OUT_F] = acc[mt][nt][r] * s + bb;
        }
    }
}

extern "C" void kernel_launch(void* const* d_in, const int* in_sizes, int n_in,
                              void* d_out, int out_size, void* d_ws, size_t ws_size,
                              hipStream_t stream) {
    const float* x     = (const float*)d_in[0];
    const int*   wp    = (const int*)d_in[1];
    const float* scale = (const float*)d_in[2];
    const float* woff  = (const float*)d_in[3];
    const float* bias  = (const float*)d_in[4];
    float* out = (float*)d_out;

    uint16_t* xb = (uint16_t*)d_ws;                      // 64 MiB
    uint16_t* wt = xb + (size_t)TOKENS * IN_F;           // 86 MiB

    xcvt_kernel<<<(TOKENS * (size_t)IN_F) / (256 * 8), 256, 0, stream>>>(x, xb);
    wdeq_kernel<<<dim3(IN_F / 64, PACKED / 32), 256, 0, stream>>>(wp, woff, wt);
    gemm_kernel<<<(TOKENS / 128) * (OUT_F / 128), 256, 0, stream>>>(xb, wt, scale, bias, out);
}